// Round 6
// baseline (1282.508 us; speedup 1.0000x reference)
//
#include <hip/hip_runtime.h>
#include <hip/hip_bf16.h>
#include <math.h>

#define H_DIM  1152
#define FL_DIM 1152
#define FH_DIM 4608
#define NTOK   32768

typedef __attribute__((ext_vector_type(8))) short bf16x8;
typedef __attribute__((ext_vector_type(4))) float floatx4;
typedef __attribute__((ext_vector_type(4))) unsigned short ushort4v;

__device__ __forceinline__ unsigned short f2bf(float f) {
  union { float f; unsigned int i; } v; v.f = f;
  return (unsigned short)((v.i + 0x7FFFu + ((v.i >> 16) & 1u)) >> 16);
}

// ---------------- fp32 -> bf16 conversion (weights) -------------------------
__global__ __launch_bounds__(256) void cvt_kernel(
    const float* __restrict__ in, unsigned short* __restrict__ out, int n4) {
  const int i = blockIdx.x * 256 + threadIdx.x;
  if (i >= n4) return;
  const float4 v = ((const float4*)in)[i];
  ushort4v o;
  o[0] = f2bf(v.x); o[1] = f2bf(v.y); o[2] = f2bf(v.z); o[3] = f2bf(v.w);
  ((ushort4v*)out)[i] = o;
}

// ------- router + x cvt: p1[t] = sigmoid(l1-l0); xb = bf16(x) ---------------
__global__ __launch_bounds__(256) void router_cvt_kernel(
    const float* __restrict__ x,   // [NTOK, H] fp32
    const float* __restrict__ rw,  // [2, H]
    const float* __restrict__ rb,  // [2]
    float* __restrict__ p1out,     // [NTOK]
    unsigned short* __restrict__ xb) {  // [NTOK, H] bf16
  const int wave = threadIdx.x >> 6;
  const int lane = threadIdx.x & 63;
  const int tok = blockIdx.x * 4 + wave;
  const float* xr = x + (size_t)tok * H_DIM;
  unsigned short* xo = xb + (size_t)tok * H_DIM;
  float s0 = 0.f, s1 = 0.f;
#pragma unroll
  for (int j = 0; j < H_DIM / 64; ++j) {
    const int h = j * 64 + lane;
    const float xv = xr[h];
    xo[h] = f2bf(xv);
    s0 += xv * rw[h];
    s1 += xv * rw[H_DIM + h];
  }
  for (int off = 32; off > 0; off >>= 1) {
    s0 += __shfl_down(s0, off);
    s1 += __shfl_down(s1, off);
  }
  if (lane == 0) {
    const float l0 = s0 + rb[0];
    const float l1 = s1 + rb[1];
    p1out[tok] = 1.f / (1.f + expf(l0 - l1));
  }
}

// ------------- shared GEMM building blocks (128x128 tile, BK=64) -------------
// LDS: 128 rows x 8 chunks of 16B; chunk column XOR-swizzled by (row&7) so the
// ds_read_b128 fragment reads are 2-way bank-aliased (free) instead of 16-way.
// global_load_lds destination is wave-uniform base + lane*16 (HW requirement).
// 32 KiB LDS/block -> 5 blocks/CU residency (round-4 showed cutting residency
// to 3 loses the inter-block MFMA/stage overlap: 543 -> 610 us. Keep 32 KiB).

// compile-time LDA: row*LDA folds to shifts/adds, chunk offsets fully hoisted
// (round-3 verified win on gemm1: 585 -> 543 us)
template <int LDA>
__device__ __forceinline__ void stage_tile(const unsigned short* __restrict__ g0,
                                           unsigned short* l0, int tid) {
  const int w = tid >> 6;
#pragma unroll
  for (int i = 0; i < 4; ++i) {
    const int c = i * 256 + tid;     // linear 16B-chunk index, 1024 total
    const int row = c >> 3;
    const int jg = (c & 7) ^ (row & 7);
    const unsigned short* g = g0 + (size_t)row * LDA + jg * 8;
    unsigned short* lp = l0 + (size_t)(i * 4 + w) * 512;  // wave-uniform base
    __builtin_amdgcn_global_load_lds((const __attribute__((address_space(1))) void*)g,
                                     (__attribute__((address_space(3))) void*)lp,
                                     16, 0, 0);
  }
}

// runtime-LDA variant (gemm2's fused K-loop: best measured form, round 0;
// round-3's split-loop compile-time version regressed gemm2 ~+50 us)
__device__ __forceinline__ void stage_tile_rt(const unsigned short* __restrict__ g0,
                                              int lda, unsigned short* l0, int tid) {
  const int w = tid >> 6;
#pragma unroll
  for (int i = 0; i < 4; ++i) {
    const int c = i * 256 + tid;
    const int row = c >> 3;
    const int jg = (c & 7) ^ (row & 7);
    const unsigned short* g = g0 + (size_t)row * lda + jg * 8;
    unsigned short* lp = l0 + (size_t)(i * 4 + w) * 512;
    __builtin_amdgcn_global_load_lds((const __attribute__((address_space(1))) void*)g,
                                     (__attribute__((address_space(3))) void*)lp,
                                     16, 0, 0);
  }
}

__device__ __forceinline__ void mma_tile(const unsigned short* As, const unsigned short* Bs,
                                         floatx4 acc[4][4], int wm, int wn, int quad, int l16) {
#pragma unroll
  for (int kk = 0; kk < 2; ++kk) {
    bf16x8 af[4], bfr[4];
#pragma unroll
    for (int mi = 0; mi < 4; ++mi) {
      const int row = wm * 64 + mi * 16 + l16;
      const int ch = (kk * 4 + quad) ^ (row & 7);
      af[mi] = *(const bf16x8*)(As + row * 64 + ch * 8);
    }
#pragma unroll
    for (int ni = 0; ni < 4; ++ni) {
      const int row = wn * 64 + ni * 16 + l16;
      const int ch = (kk * 4 + quad) ^ (row & 7);
      bfr[ni] = *(const bf16x8*)(Bs + row * 64 + ch * 8);
    }
#pragma unroll
    for (int mi = 0; mi < 4; ++mi)
#pragma unroll
      for (int ni = 0; ni < 4; ++ni)
        acc[mi][ni] = __builtin_amdgcn_mfma_f32_16x16x32_bf16(af[mi], bfr[ni], acc[mi][ni], 0, 0, 0);
  }
}

// XCD-grouped swizzle (A-resident): each XCD walks one M-tile across all
// N-tiles. Fallback when gm % 32 != 0.
__device__ __forceinline__ void swizzle(int b, int gm, int gn, int& m, int& n) {
  const int xcd = b & 7;
  const int idx = b >> 3;
  const int mloc = idx / gn;
  n = idx - mloc * gn;
  m = xcd * (gm >> 3) + mloc;
}

// Two-level swizzle (round-5 verified on gemm1: FETCH 1.61 GB -> 0.49 GB,
// 543 -> 511 us): within each XCD, M-tiles advance in groups of 4, order
// (mgroup, n, mlocal). Reuse distances become short: W-panel(n) consumed by 4
// back-to-back blocks; A-panel(ml) reused every 4 blocks across all n -> both
// staging operands are L2-hits. Requires gm % 32 == 0; falls back otherwise.
__device__ __forceinline__ void swizzle_g4(int b, int gm, int gn, int& m, int& n) {
  if ((gm & 31) != 0) { swizzle(b, gm, gn, m, n); return; }
  const int xcd = b & 7;
  const int idx = b >> 3;
  const int grp = idx / (gn * 4);
  const int rem = idx - grp * (gn * 4);
  n = rem >> 2;
  const int ml = rem & 3;
  m = xcd * (gm >> 3) + grp * 4 + ml;
}

// - GEMM1 fused: Hl/Hh[t,f] = scale * gelu(x.W1^T + b1), scale = (1-p) or p --
__global__ __launch_bounds__(256, 2) void gemm1_fused_kernel(
    const unsigned short* __restrict__ Xb,   // [C, H] bf16
    const unsigned short* __restrict__ W1l,  // [FL, H] bf16
    const unsigned short* __restrict__ W1h,  // [FH, H] bf16
    const float* __restrict__ b1l,           // [FL] fp32
    const float* __restrict__ b1h,           // [FH] fp32
    const float* __restrict__ p1,            // [C]
    unsigned short* __restrict__ Hl,         // [C, FL] bf16
    unsigned short* __restrict__ Hh,         // [C, FH] bf16
    int gm) {
  __shared__ __align__(16) unsigned short As[128 * 64];
  __shared__ __align__(16) unsigned short Bs[128 * 64];
  const int tid = threadIdx.x;
  const int w = tid >> 6, lane = tid & 63;
  const int wm = w >> 1, wn = w & 1;
  const int quad = lane >> 4, l16 = lane & 15;

  int m, n;
  swizzle_g4(blockIdx.x, gm, 45, m, n);        // 9 light + 36 heavy N-tiles
  const int tm = m * 128;
  const bool heavy = n >= 9;
  const int nl = heavy ? n - 9 : n;
  const int tn = nl * 128;
  const int F = heavy ? FH_DIM : FL_DIM;
  const unsigned short* W = heavy ? W1h : W1l;
  const float* bias_p = heavy ? b1h : b1l;
  unsigned short* Hout = heavy ? Hh : Hl;

  floatx4 acc[4][4];
#pragma unroll
  for (int i = 0; i < 4; ++i)
#pragma unroll
    for (int j = 0; j < 4; ++j) acc[i][j] = (floatx4){0.f, 0.f, 0.f, 0.f};

  const unsigned short* Abase = Xb + (size_t)tm * H_DIM;
  const unsigned short* Bbase = W + (size_t)tn * H_DIM;

  for (int kt = 0; kt < H_DIM / 64; ++kt) {
    __syncthreads();
    stage_tile<H_DIM>(Abase + kt * 64, As, tid);
    stage_tile<H_DIM>(Bbase + kt * 64, Bs, tid);
    __syncthreads();
    mma_tile(As, Bs, acc, wm, wn, quad, l16);
  }

  float bias[4];
#pragma unroll
  for (int ni = 0; ni < 4; ++ni) bias[ni] = bias_p[tn + wn * 64 + ni * 16 + l16];

#pragma unroll
  for (int mi = 0; mi < 4; ++mi) {
#pragma unroll
    for (int r = 0; r < 4; ++r) {
      const int gtok = tm + wm * 64 + mi * 16 + quad * 4 + r;
      const float pv = p1[gtok];
      const float scale = heavy ? pv : (1.f - pv);
#pragma unroll
      for (int ni = 0; ni < 4; ++ni) {
        const int col = tn + wn * 64 + ni * 16 + l16;
        const float v = acc[mi][ni][r] + bias[ni];
        const float g = 0.5f * v * (1.f + erff(v * 0.70710678118f));
        Hout[(size_t)gtok * F + col] = f2bf(g * scale);
      }
    }
  }
}

// -- GEMM2: out[t,h] = Hl.W2l^T + Hh.W2h^T + (1-p1)b2l + p1*b2h (K = 5760) ---
// Single fused K-loop (runtime lda) -- best measured gemm2 form (round 0).
// Round 6: swizzle_g4 (same lever as gemm1's round-5 win) + LLC-sized token
// chunks (host side) so the H operand is Infinity-Cache-resident.
__global__ __launch_bounds__(256, 2) void gemm2_kernel(
    const unsigned short* __restrict__ Hl,   // [C, FL] bf16
    const unsigned short* __restrict__ Hh,   // [C, FH] bf16
    const unsigned short* __restrict__ W2l,  // [H, FL] bf16
    const unsigned short* __restrict__ W2h,  // [H, FH] bf16
    const float* __restrict__ b2l,           // [H] fp32
    const float* __restrict__ b2h,           // [H] fp32
    const float* __restrict__ p1,            // [C]
    float* __restrict__ Out,                 // [C, H] fp32
    int gm) {
  __shared__ __align__(16) unsigned short As[128 * 64];
  __shared__ __align__(16) unsigned short Bs[128 * 64];
  const int tid = threadIdx.x;
  const int w = tid >> 6, lane = tid & 63;
  const int wm = w >> 1, wn = w & 1;
  const int quad = lane >> 4, l16 = lane & 15;

  int m, n;
  swizzle_g4(blockIdx.x, gm, 9, m, n);
  const int tm = m * 128;
  const int tn = n * 128;

  floatx4 acc[4][4];
#pragma unroll
  for (int i = 0; i < 4; ++i)
#pragma unroll
    for (int j = 0; j < 4; ++j) acc[i][j] = (floatx4){0.f, 0.f, 0.f, 0.f};

  const int KT1 = FL_DIM / 64;              // 18
  const int KTALL = KT1 + FH_DIM / 64;      // 90
  for (int kt = 0; kt < KTALL; ++kt) {
    const unsigned short* Ab;
    const unsigned short* Bb;
    int lda;
    if (kt < KT1) {
      Ab = Hl + (size_t)tm * FL_DIM + kt * 64;
      Bb = W2l + (size_t)tn * FL_DIM + kt * 64;
      lda = FL_DIM;
    } else {
      const int k2 = kt - KT1;
      Ab = Hh + (size_t)tm * FH_DIM + k2 * 64;
      Bb = W2h + (size_t)tn * FH_DIM + k2 * 64;
      lda = FH_DIM;
    }
    __syncthreads();
    stage_tile_rt(Ab, lda, As, tid);
    stage_tile_rt(Bb, lda, Bs, tid);
    __syncthreads();
    mma_tile(As, Bs, acc, wm, wn, quad, l16);
  }

  float bl[4], bh[4];
#pragma unroll
  for (int ni = 0; ni < 4; ++ni) {
    const int col = tn + wn * 64 + ni * 16 + l16;
    bl[ni] = b2l[col];
    bh[ni] = b2h[col];
  }

#pragma unroll
  for (int mi = 0; mi < 4; ++mi) {
#pragma unroll
    for (int r = 0; r < 4; ++r) {
      const int gtok = tm + wm * 64 + mi * 16 + quad * 4 + r;
      const float pv = p1[gtok];
#pragma unroll
      for (int ni = 0; ni < 4; ++ni) {
        const int col = tn + wn * 64 + ni * 16 + l16;
        Out[(size_t)gtok * H_DIM + col] = acc[mi][ni][r] + bl[ni] + pv * (bh[ni] - bl[ni]);
      }
    }
  }
}

extern "C" void kernel_launch(void* const* d_in, const int* in_sizes, int n_in,
                              void* d_out, int out_size, void* d_ws, size_t ws_size,
                              hipStream_t stream) {
  const float* x   = (const float*)d_in[0];
  const float* rw  = (const float*)d_in[1];
  const float* rb  = (const float*)d_in[2];
  const float* lw1 = (const float*)d_in[3];
  const float* lb1 = (const float*)d_in[4];
  const float* lw2 = (const float*)d_in[5];
  const float* lb2 = (const float*)d_in[6];
  const float* hw1 = (const float*)d_in[7];
  const float* hb1 = (const float*)d_in[8];
  const float* hw2 = (const float*)d_in[9];
  const float* hb2 = (const float*)d_in[10];
  float* out = (float*)d_out;

  // ---- workspace layout ----
  const size_t N_LW = (size_t)FL_DIM * H_DIM;
  const size_t N_HW = (size_t)FH_DIM * H_DIM;
  char* p = (char*)d_ws;
  float* p1 = (float*)p;                     p += (size_t)NTOK * 4;
  unsigned short* lw1b = (unsigned short*)p; p += N_LW * 2;
  unsigned short* hw1b = (unsigned short*)p; p += N_HW * 2;
  unsigned short* lw2b = (unsigned short*)p; p += N_LW * 2;
  unsigned short* hw2b = (unsigned short*)p; p += N_HW * 2;
  unsigned short* xb   = (unsigned short*)p; p += (size_t)NTOK * H_DIM * 2;
  const size_t fixed = (size_t)(p - (char*)d_ws);

  // tokens per chunk: hl (C*FL*2) + hh (C*FH*2) = C*11520 bytes.
  // Round-5 counters proved C was 32768 (gemm1 WRITE_SIZE == NTOK*11520):
  // the 377 MB H buffer exceeds the 256 MB Infinity Cache, so gemm1's H
  // writes and gemm2's H reads were HBM round-trips. Cap C at 16384
  // (H-chunk = 189 MB, LLC-resident with W2) while keeping gemm2's grid at
  // 1152 blocks (~4.5/CU residency) and gm % 32 == 0 for swizzle_g4.
  int C = NTOK;
  while (C > 1024 && fixed + (size_t)C * 11520 > ws_size) C >>= 1;
  if (C > 16384) C = 16384;
  unsigned short* hl = (unsigned short*)p;
  unsigned short* hh = hl + (size_t)C * FL_DIM;

  // ---- weight conversions (fp32 -> bf16) ----
  cvt_kernel<<<(int)(N_LW / 1024), 256, 0, stream>>>(lw1, lw1b, (int)(N_LW / 4));
  cvt_kernel<<<(int)(N_HW / 1024), 256, 0, stream>>>(hw1, hw1b, (int)(N_HW / 4));
  cvt_kernel<<<(int)(N_LW / 1024), 256, 0, stream>>>(lw2, lw2b, (int)(N_LW / 4));
  cvt_kernel<<<(int)(N_HW / 1024), 256, 0, stream>>>(hw2, hw2b, (int)(N_HW / 4));

  router_cvt_kernel<<<NTOK / 4, 256, 0, stream>>>(x, rw, rb, p1, xb);

  for (int c0 = 0; c0 < NTOK; c0 += C) {
    const int gm = C / 128;
    gemm1_fused_kernel<<<gm * 45, 256, 0, stream>>>(
        xb + (size_t)c0 * H_DIM, lw1b, hw1b, lb1, hb1, p1 + c0, hl, hh, gm);
    gemm2_kernel<<<gm * 9, 256, 0, stream>>>(
        hl, hh, lw2b, hw2b, lb2, hb2, p1 + c0, out + (size_t)c0 * H_DIM, gm);
  }
}

// Round 7
// 1233.600 us; speedup vs baseline: 1.0396x; 1.0396x over previous
//
#include <hip/hip_runtime.h>
#include <hip/hip_bf16.h>
#include <math.h>

#define H_DIM  1152
#define FL_DIM 1152
#define FH_DIM 4608
#define NTOK   32768

typedef __attribute__((ext_vector_type(8))) short bf16x8;
typedef __attribute__((ext_vector_type(4))) float floatx4;
typedef __attribute__((ext_vector_type(4))) unsigned short ushort4v;

__device__ __forceinline__ unsigned short f2bf(float f) {
  union { float f; unsigned int i; } v; v.f = f;
  return (unsigned short)((v.i + 0x7FFFu + ((v.i >> 16) & 1u)) >> 16);
}

// ---------------- fp32 -> bf16 conversion (weights, flat) -------------------
__global__ __launch_bounds__(256) void cvt_kernel(
    const float* __restrict__ in, unsigned short* __restrict__ out, int n4) {
  const int i = blockIdx.x * 256 + threadIdx.x;
  if (i >= n4) return;
  const float4 v = ((const float4*)in)[i];
  ushort4v o;
  o[0] = f2bf(v.x); o[1] = f2bf(v.y); o[2] = f2bf(v.z); o[3] = f2bf(v.w);
  ((ushort4v*)out)[i] = o;
}

// ---- fp32 -> bf16 transcode into 128x128 tile-blocked layout ---------------
// in: fp32 [RT*128, ld] row-major; out: bf16 [RT*CT tiles][128][128] dense.
// Dense tiles give gemm2 staging lda=128 (256B row stride -> all TCC channels;
// the flat [H,F] layout's 9216B stride mapped to only 8/32 channels).
__global__ __launch_bounds__(256) void cvt_block_kernel(
    const float* __restrict__ in, unsigned short* __restrict__ out,
    int ct, int ld) {
  const int tile = blockIdx.x;
  const int tr = tile / ct, tc = tile - tr * ct;
  const float* src = in + (size_t)tr * 128 * ld + tc * 128;
  unsigned short* dst = out + (size_t)tile * (128 * 128);
  const int tid = threadIdx.x;
#pragma unroll
  for (int i = 0; i < 16; ++i) {
    const int idx = i * 256 + tid;     // float4 index within tile, 0..4095
    const int row = idx >> 5;
    const int c4 = idx & 31;
    const float4 v = *(const float4*)(src + (size_t)row * ld + c4 * 4);
    ushort4v o;
    o[0] = f2bf(v.x); o[1] = f2bf(v.y); o[2] = f2bf(v.z); o[3] = f2bf(v.w);
    *(ushort4v*)(dst + row * 128 + c4 * 4) = o;
  }
}

// ------- router + x cvt: p1[t] = sigmoid(l1-l0); xb = bf16(x) ---------------
__global__ __launch_bounds__(256) void router_cvt_kernel(
    const float* __restrict__ x,   // [NTOK, H] fp32
    const float* __restrict__ rw,  // [2, H]
    const float* __restrict__ rb,  // [2]
    float* __restrict__ p1out,     // [NTOK]
    unsigned short* __restrict__ xb) {  // [NTOK, H] bf16
  const int wave = threadIdx.x >> 6;
  const int lane = threadIdx.x & 63;
  const int tok = blockIdx.x * 4 + wave;
  const float* xr = x + (size_t)tok * H_DIM;
  unsigned short* xo = xb + (size_t)tok * H_DIM;
  float s0 = 0.f, s1 = 0.f;
#pragma unroll
  for (int j = 0; j < H_DIM / 64; ++j) {
    const int h = j * 64 + lane;
    const float xv = xr[h];
    xo[h] = f2bf(xv);
    s0 += xv * rw[h];
    s1 += xv * rw[H_DIM + h];
  }
  for (int off = 32; off > 0; off >>= 1) {
    s0 += __shfl_down(s0, off);
    s1 += __shfl_down(s1, off);
  }
  if (lane == 0) {
    const float l0 = s0 + rb[0];
    const float l1 = s1 + rb[1];
    p1out[tok] = 1.f / (1.f + expf(l0 - l1));
  }
}

// ------------- shared GEMM building blocks (128x128 tile, BK=64) -------------
// LDS: 128 rows x 8 chunks of 16B; chunk column XOR-swizzled by (row&7) so the
// ds_read_b128 fragment reads are 2-way bank-aliased (free) instead of 16-way.
// global_load_lds destination is wave-uniform base + lane*16 (HW requirement).
// 32 KiB LDS/block -> 5 blocks/CU (r4: pinning 3 lost inter-block overlap).

// compile-time LDA: row*LDA folds to shifts/adds, chunk offsets fully hoisted
// (r3 verified on gemm1: 585 -> 543 us). With blocked intermediates, gemm2
// uses LDA=128 for every K-step.
template <int LDA>
__device__ __forceinline__ void stage_tile(const unsigned short* __restrict__ g0,
                                           unsigned short* l0, int tid) {
  const int w = tid >> 6;
#pragma unroll
  for (int i = 0; i < 4; ++i) {
    const int c = i * 256 + tid;     // linear 16B-chunk index, 1024 total
    const int row = c >> 3;
    const int jg = (c & 7) ^ (row & 7);
    const unsigned short* g = g0 + (size_t)row * LDA + jg * 8;
    unsigned short* lp = l0 + (size_t)(i * 4 + w) * 512;  // wave-uniform base
    __builtin_amdgcn_global_load_lds((const __attribute__((address_space(1))) void*)g,
                                     (__attribute__((address_space(3))) void*)lp,
                                     16, 0, 0);
  }
}

__device__ __forceinline__ void mma_tile(const unsigned short* As, const unsigned short* Bs,
                                         floatx4 acc[4][4], int wm, int wn, int quad, int l16) {
#pragma unroll
  for (int kk = 0; kk < 2; ++kk) {
    bf16x8 af[4], bfr[4];
#pragma unroll
    for (int mi = 0; mi < 4; ++mi) {
      const int row = wm * 64 + mi * 16 + l16;
      const int ch = (kk * 4 + quad) ^ (row & 7);
      af[mi] = *(const bf16x8*)(As + row * 64 + ch * 8);
    }
#pragma unroll
    for (int ni = 0; ni < 4; ++ni) {
      const int row = wn * 64 + ni * 16 + l16;
      const int ch = (kk * 4 + quad) ^ (row & 7);
      bfr[ni] = *(const bf16x8*)(Bs + row * 64 + ch * 8);
    }
#pragma unroll
    for (int mi = 0; mi < 4; ++mi)
#pragma unroll
      for (int ni = 0; ni < 4; ++ni)
        acc[mi][ni] = __builtin_amdgcn_mfma_f32_16x16x32_bf16(af[mi], bfr[ni], acc[mi][ni], 0, 0, 0);
  }
}

// XCD-grouped swizzle (A-resident): each XCD walks one M-tile across all
// N-tiles. Used by gemm2 (r5-best config) and as fallback.
__device__ __forceinline__ void swizzle(int b, int gm, int gn, int& m, int& n) {
  const int xcd = b & 7;
  const int idx = b >> 3;
  const int mloc = idx / gn;
  n = idx - mloc * gn;
  m = xcd * (gm >> 3) + mloc;
}

// Two-level swizzle (r5 verified on gemm1: FETCH 1.61 GB -> 0.49 GB,
// 543 -> 511 us): within each XCD, M-tiles advance in groups of 4, order
// (mgroup, n, mlocal) -> short reuse distances for both W-panels and
// A-panels; staging becomes L2-hot. Requires gm % 32 == 0; else fallback.
__device__ __forceinline__ void swizzle_g4(int b, int gm, int gn, int& m, int& n) {
  if ((gm & 31) != 0) { swizzle(b, gm, gn, m, n); return; }
  const int xcd = b & 7;
  const int idx = b >> 3;
  const int grp = idx / (gn * 4);
  const int rem = idx - grp * (gn * 4);
  n = rem >> 2;
  const int ml = rem & 3;
  m = xcd * (gm >> 3) + grp * 4 + ml;
}

// - GEMM1 fused: Hl/Hh[t,f] = scale * gelu(x.W1^T + b1), scale = (1-p) or p --
// Hl/Hh are written in 128x128 tile-blocked layout: [mtile][ftile][128][128].
__global__ __launch_bounds__(256, 2) void gemm1_fused_kernel(
    const unsigned short* __restrict__ Xb,   // [C, H] bf16
    const unsigned short* __restrict__ W1l,  // [FL, H] bf16
    const unsigned short* __restrict__ W1h,  // [FH, H] bf16
    const float* __restrict__ b1l,           // [FL] fp32
    const float* __restrict__ b1h,           // [FH] fp32
    const float* __restrict__ p1,            // [C]
    unsigned short* __restrict__ Hl,         // [C/128][9][128][128] bf16
    unsigned short* __restrict__ Hh,         // [C/128][36][128][128] bf16
    int gm) {
  __shared__ __align__(16) unsigned short As[128 * 64];
  __shared__ __align__(16) unsigned short Bs[128 * 64];
  const int tid = threadIdx.x;
  const int w = tid >> 6, lane = tid & 63;
  const int wm = w >> 1, wn = w & 1;
  const int quad = lane >> 4, l16 = lane & 15;

  int m, n;
  swizzle_g4(blockIdx.x, gm, 45, m, n);        // 9 light + 36 heavy N-tiles
  const int tm = m * 128;
  const bool heavy = n >= 9;
  const int nl = heavy ? n - 9 : n;
  const int tn = nl * 128;
  const unsigned short* W = heavy ? W1h : W1l;
  const float* bias_p = heavy ? b1h : b1l;

  floatx4 acc[4][4];
#pragma unroll
  for (int i = 0; i < 4; ++i)
#pragma unroll
    for (int j = 0; j < 4; ++j) acc[i][j] = (floatx4){0.f, 0.f, 0.f, 0.f};

  const unsigned short* Abase = Xb + (size_t)tm * H_DIM;
  const unsigned short* Bbase = W + (size_t)tn * H_DIM;

  for (int kt = 0; kt < H_DIM / 64; ++kt) {
    __syncthreads();
    stage_tile<H_DIM>(Abase + kt * 64, As, tid);
    stage_tile<H_DIM>(Bbase + kt * 64, Bs, tid);
    __syncthreads();
    mma_tile(As, Bs, acc, wm, wn, quad, l16);
  }

  float bias[4];
#pragma unroll
  for (int ni = 0; ni < 4; ++ni) bias[ni] = bias_p[tn + wn * 64 + ni * 16 + l16];

  // blocked destination tile: (mtile=m, ftile=nl)
  unsigned short* dst = (heavy ? Hh + ((size_t)m * 36 + nl) * 16384
                               : Hl + ((size_t)m * 9 + nl) * 16384);
#pragma unroll
  for (int mi = 0; mi < 4; ++mi) {
#pragma unroll
    for (int r = 0; r < 4; ++r) {
      const int lt = wm * 64 + mi * 16 + quad * 4 + r;   // token within tile
      const float pv = p1[tm + lt];
      const float scale = heavy ? pv : (1.f - pv);
#pragma unroll
      for (int ni = 0; ni < 4; ++ni) {
        const int lc = wn * 64 + ni * 16 + l16;          // col within tile
        const float v = acc[mi][ni][r] + bias[ni];
        const float g = 0.5f * v * (1.f + erff(v * 0.70710678118f));
        dst[lt * 128 + lc] = f2bf(g * scale);
      }
    }
  }
}

// -- GEMM2: out[t,h] = Hl.W2l^T + Hh.W2h^T + (1-p1)b2l + p1*b2h (K = 5760) ---
// All four staged operands are 128x128 tile-blocked -> lda=128 compile-time,
// dense 32KB tiles (256B row stride spreads over all TCC channels; the flat
// heavy-phase stride 9216B hit only 8/32 channels).
__global__ __launch_bounds__(256, 2) void gemm2_kernel(
    const unsigned short* __restrict__ Hl,   // [C/128][9][128][128] bf16
    const unsigned short* __restrict__ Hh,   // [C/128][36][128][128] bf16
    const unsigned short* __restrict__ W2l,  // [9][9][128][128] bf16
    const unsigned short* __restrict__ W2h,  // [9][36][128][128] bf16
    const float* __restrict__ b2l,           // [H] fp32
    const float* __restrict__ b2h,           // [H] fp32
    const float* __restrict__ p1,            // [C]
    float* __restrict__ Out,                 // [C, H] fp32
    int gm) {
  __shared__ __align__(16) unsigned short As[128 * 64];
  __shared__ __align__(16) unsigned short Bs[128 * 64];
  const int tid = threadIdx.x;
  const int w = tid >> 6, lane = tid & 63;
  const int wm = w >> 1, wn = w & 1;
  const int quad = lane >> 4, l16 = lane & 15;

  int m, n;
  swizzle(blockIdx.x, gm, 9, m, n);
  const int tm = m * 128;
  const int tn = n * 128;

  floatx4 acc[4][4];
#pragma unroll
  for (int i = 0; i < 4; ++i)
#pragma unroll
    for (int j = 0; j < 4; ++j) acc[i][j] = (floatx4){0.f, 0.f, 0.f, 0.f};

  const int KT1 = FL_DIM / 64;              // 18
  const int KTALL = KT1 + FH_DIM / 64;      // 90
  for (int kt = 0; kt < KTALL; ++kt) {
    const unsigned short* Ab;
    const unsigned short* Bb;
    if (kt < KT1) {
      const int ft = kt >> 1, off = (kt & 1) * 64;
      Ab = Hl + ((size_t)m * 9 + ft) * 16384 + off;
      Bb = W2l + ((size_t)n * 9 + ft) * 16384 + off;
    } else {
      const int k2 = kt - KT1;
      const int ft = k2 >> 1, off = (k2 & 1) * 64;
      Ab = Hh + ((size_t)m * 36 + ft) * 16384 + off;
      Bb = W2h + ((size_t)n * 36 + ft) * 16384 + off;
    }
    __syncthreads();
    stage_tile<128>(Ab, As, tid);
    stage_tile<128>(Bb, Bs, tid);
    __syncthreads();
    mma_tile(As, Bs, acc, wm, wn, quad, l16);
  }

  float bl[4], bh[4];
#pragma unroll
  for (int ni = 0; ni < 4; ++ni) {
    const int col = tn + wn * 64 + ni * 16 + l16;
    bl[ni] = b2l[col];
    bh[ni] = b2h[col];
  }

#pragma unroll
  for (int mi = 0; mi < 4; ++mi) {
#pragma unroll
    for (int r = 0; r < 4; ++r) {
      const int gtok = tm + wm * 64 + mi * 16 + quad * 4 + r;
      const float pv = p1[gtok];
#pragma unroll
      for (int ni = 0; ni < 4; ++ni) {
        const int col = tn + wn * 64 + ni * 16 + l16;
        Out[(size_t)gtok * H_DIM + col] = acc[mi][ni][r] + bl[ni] + pv * (bh[ni] - bl[ni]);
      }
    }
  }
}

extern "C" void kernel_launch(void* const* d_in, const int* in_sizes, int n_in,
                              void* d_out, int out_size, void* d_ws, size_t ws_size,
                              hipStream_t stream) {
  const float* x   = (const float*)d_in[0];
  const float* rw  = (const float*)d_in[1];
  const float* rb  = (const float*)d_in[2];
  const float* lw1 = (const float*)d_in[3];
  const float* lb1 = (const float*)d_in[4];
  const float* lw2 = (const float*)d_in[5];
  const float* lb2 = (const float*)d_in[6];
  const float* hw1 = (const float*)d_in[7];
  const float* hb1 = (const float*)d_in[8];
  const float* hw2 = (const float*)d_in[9];
  const float* hb2 = (const float*)d_in[10];
  float* out = (float*)d_out;

  // ---- workspace layout (sizes identical to round 5; blocked = permuted) ----
  const size_t N_LW = (size_t)FL_DIM * H_DIM;
  const size_t N_HW = (size_t)FH_DIM * H_DIM;
  char* p = (char*)d_ws;
  float* p1 = (float*)p;                     p += (size_t)NTOK * 4;
  unsigned short* lw1b = (unsigned short*)p; p += N_LW * 2;
  unsigned short* hw1b = (unsigned short*)p; p += N_HW * 2;
  unsigned short* lw2b = (unsigned short*)p; p += N_LW * 2;   // blocked [9][9]
  unsigned short* hw2b = (unsigned short*)p; p += N_HW * 2;   // blocked [9][36]
  unsigned short* xb   = (unsigned short*)p; p += (size_t)NTOK * H_DIM * 2;
  const size_t fixed = (size_t)(p - (char*)d_ws);

  // tokens per chunk: hl (C*FL*2) + hh (C*FH*2) = C*11520 bytes
  int C = NTOK;
  while (C > 1024 && fixed + (size_t)C * 11520 > ws_size) C >>= 1;
  unsigned short* hl = (unsigned short*)p;                    // blocked [C/128][9]
  unsigned short* hh = hl + (size_t)C * FL_DIM;               // blocked [C/128][36]

  // ---- weight conversions ----
  cvt_kernel<<<(int)(N_LW / 1024), 256, 0, stream>>>(lw1, lw1b, (int)(N_LW / 4));
  cvt_kernel<<<(int)(N_HW / 1024), 256, 0, stream>>>(hw1, hw1b, (int)(N_HW / 4));
  // W2: blocked transcode (dense 128x128 tiles for gemm2 staging)
  cvt_block_kernel<<<9 * 9, 256, 0, stream>>>(lw2, lw2b, 9, FL_DIM);
  cvt_block_kernel<<<9 * 36, 256, 0, stream>>>(hw2, hw2b, 36, FH_DIM);

  router_cvt_kernel<<<NTOK / 4, 256, 0, stream>>>(x, rw, rb, p1, xb);

  for (int c0 = 0; c0 < NTOK; c0 += C) {
    const int gm = C / 128;
    gemm1_fused_kernel<<<gm * 45, 256, 0, stream>>>(
        xb + (size_t)c0 * H_DIM, lw1b, hw1b, lb1, hb1, p1 + c0, hl, hh, gm);
    gemm2_kernel<<<gm * 9, 256, 0, stream>>>(
        hl, hh, lw2b, hw2b, lb2, hb2, p1 + c0, out + (size_t)c0 * H_DIM, gm);
  }
}